// Round 1
// baseline (15185.236 us; speedup 1.0000x reference)
//
#include <hip/hip_runtime.h>
#include <math.h>

#define SEQ   1024
#define BATCH 256
#define IND   256
#define HID   256
#define KTOT  512   // IND + HID

// One kernel per timestep. Grid: blockIdx.x = j-tile (16 h-cols), blockIdx.y =
// b-tile (16 batch rows). 256 threads; thread (bb=tid>>4, jj=tid&15) computes
// all 4 gate dots for output (b0+bb, j0+jj) -> epilogue is thread-local,
// c-state update is an exclusive RMW (no races).
//
// State plumbing (no d_ws needed):
//   h history  = the stacked output itself: step s reads h from out[s-1]
//   c state    = the cx slot of d_out (exclusively owned per (b,j))
//   final hx   = written by the last step alongside stacked[1023]
__global__ __launch_bounds__(256) void lstm_step(
    const float* __restrict__ x,      // [SEQ, BATCH, IND]
    const float* __restrict__ h0,     // [BATCH, HID]
    const float* __restrict__ c0,     // [BATCH, HID]
    const float* __restrict__ Wf, const float* __restrict__ bf,
    const float* __restrict__ Wi, const float* __restrict__ bi,
    const float* __restrict__ Wg, const float* __restrict__ bg,
    const float* __restrict__ Wo, const float* __restrict__ bo,
    float* __restrict__ out,          // stacked [SEQ, BATCH, HID]
    float* __restrict__ cx,           // running c state [BATCH, HID]
    float* __restrict__ hx,           // final h slot  [BATCH, HID]
    int s)
{
    // A: 16 rows x 512 k, row stride 516 (pad 4 -> banks 4*bb+k, conflict-free)
    __shared__ __align__(16) float A_lds[16][516];
    // W chunk: 4 gates x 16 j x 64 k, k stride 68 (2-way aliasing only = free)
    __shared__ __align__(16) float W_lds[4][16][68];

    const int tid = threadIdx.x;
    const int j0  = blockIdx.x * 16;
    const int b0  = blockIdx.y * 16;

    // ---- Stage A tile (combined = [x_s | h_{s-1}]) into LDS, float4 coalesced
    const float* hsrc = (s == 0) ? h0 : (out + (size_t)(s - 1) * (BATCH * HID));
    #pragma unroll
    for (int it = 0; it < 8; ++it) {
        int f   = tid + 256 * it;
        int row = f >> 7;             // 0..15
        int k   = (f & 127) << 2;     // 0..508 step 4
        float4 v;
        if (k < IND) {
            v = *reinterpret_cast<const float4*>(
                    x + ((size_t)s * BATCH + (b0 + row)) * IND + k);
        } else {
            v = *reinterpret_cast<const float4*>(
                    hsrc + (size_t)(b0 + row) * HID + (k - IND));
        }
        *reinterpret_cast<float4*>(&A_lds[row][k]) = v;
    }

    const int bb = tid >> 4;
    const int jj = tid & 15;

    float acc0 = 0.f, acc1 = 0.f, acc2 = 0.f, acc3 = 0.f;

    // ---- K loop in chunks of 64
    for (int kc = 0; kc < 8; ++kc) {
        // stage W chunk: for each gate, 16 rows x 64 k (float4 coalesced)
        {
            const int j  = tid >> 4;
            const int kq = tid & 15;
            #pragma unroll
            for (int g = 0; g < 4; ++g) {
                const float* wp = (g == 0) ? Wf : (g == 1) ? Wi : (g == 2) ? Wg : Wo;
                float4 v = *reinterpret_cast<const float4*>(
                    wp + (size_t)(j0 + j) * KTOT + kc * 64 + kq * 4);
                *reinterpret_cast<float4*>(&W_lds[g][j][kq * 4]) = v;
            }
        }
        __syncthreads();
        #pragma unroll
        for (int q = 0; q < 16; ++q) {
            float4 a  = *reinterpret_cast<const float4*>(&A_lds[bb][kc * 64 + q * 4]);
            float4 w0 = *reinterpret_cast<const float4*>(&W_lds[0][jj][q * 4]);
            float4 w1 = *reinterpret_cast<const float4*>(&W_lds[1][jj][q * 4]);
            float4 w2 = *reinterpret_cast<const float4*>(&W_lds[2][jj][q * 4]);
            float4 w3 = *reinterpret_cast<const float4*>(&W_lds[3][jj][q * 4]);
            acc0 += a.x * w0.x + a.y * w0.y + a.z * w0.z + a.w * w0.w;
            acc1 += a.x * w1.x + a.y * w1.y + a.z * w1.z + a.w * w1.w;
            acc2 += a.x * w2.x + a.y * w2.y + a.z * w2.z + a.w * w2.w;
            acc3 += a.x * w3.x + a.y * w3.y + a.z * w3.z + a.w * w3.w;
        }
        __syncthreads();
    }

    // ---- Epilogue (thread-local; exclusive ownership of (b,j))
    const int b   = b0 + bb;
    const int j   = j0 + jj;
    const int idx = b * HID + j;

    float zf = acc0 + bf[j];
    float zi = acc1 + bi[j];
    float zg = acc2 + bg[j];
    float zo = acc3 + bo[j];

    float fg = 1.f / (1.f + expf(-zf));
    float ig = 1.f / (1.f + expf(-zi));
    float gg = tanhf(zg);
    float og = 1.f / (1.f + expf(-zo));

    float cprev = (s == 0) ? c0[idx] : cx[idx];
    float c     = fg * cprev + ig * gg;
    cx[idx]     = c;
    float h     = og * tanhf(c);

    out[(size_t)s * (BATCH * HID) + idx] = h;
    if (s == SEQ - 1) hx[idx] = h;
}

extern "C" void kernel_launch(void* const* d_in, const int* in_sizes, int n_in,
                              void* d_out, int out_size, void* d_ws, size_t ws_size,
                              hipStream_t stream) {
    const float* x  = (const float*)d_in[0];
    const float* h0 = (const float*)d_in[1];
    const float* c0 = (const float*)d_in[2];
    const float* Wf = (const float*)d_in[3];
    const float* bf = (const float*)d_in[4];
    const float* Wi = (const float*)d_in[5];
    const float* bi = (const float*)d_in[6];
    const float* Wg = (const float*)d_in[7];
    const float* bg = (const float*)d_in[8];
    const float* Wo = (const float*)d_in[9];
    const float* bo = (const float*)d_in[10];

    float* out = (float*)d_out;
    float* hx  = out + (size_t)SEQ * BATCH * HID;
    float* cxp = hx + BATCH * HID;

    dim3 grid(16, 16), block(256);
    for (int s = 0; s < SEQ; ++s) {
        lstm_step<<<grid, block, 0, stream>>>(x, h0, c0, Wf, bf, Wi, bi,
                                              Wg, bg, Wo, bo, out, cxp, hx, s);
    }
}

// Round 2
// 9698.711 us; speedup vs baseline: 1.5657x; 1.5657x over previous
//
#include <hip/hip_runtime.h>
#include <hip/hip_bf16.h>
#include <math.h>

#define SEQ   1024
#define BATCH 256
#define IND   256
#define HID   256
#define KTOT  512
#define NGATE 4

// ws layout:
//   Wb : bf16 [4][256][512], pre-swizzled rows (1 MiB)   @ offset 0
//   hb : bf16 [2][256][256], pre-swizzled rows (256 KiB) @ offset 1 MiB
#define WB_BYTES (NGATE * HID * KTOT * 2)
#define HB_BYTES (BATCH * HID * 2)

typedef float  f32x4  __attribute__((ext_vector_type(4)));
typedef short  bf16x8 __attribute__((ext_vector_type(8)));

__device__ __forceinline__ short f2bf(float x) {
    __hip_bfloat16 h = __float2bfloat16(x);
    return *reinterpret_cast<short*>(&h);
}

__device__ __forceinline__ void gload_lds16(const void* g, void* l) {
    __builtin_amdgcn_global_load_lds(
        (const __attribute__((address_space(1))) unsigned int*)g,
        (__attribute__((address_space(3))) unsigned int*)l, 16, 0, 0);
}

__device__ __forceinline__ float sigmoid_f(float z) {
    return 1.f / (1.f + __expf(-z));
}
__device__ __forceinline__ float tanh_f(float v) {
    // 2*sigmoid(2v)-1; saturates cleanly at +-1 without NaN at extremes
    return 2.f / (1.f + __expf(-2.f * v)) - 1.f;
}

// ---------------- prep kernels (run every call; deterministic) ----------------

// W fp32 [256][512] x4 gates -> Wb bf16 [g][j][k], bytes within each 1 KiB row
// placed at (2k) ^ ((j&7)<<4) so that linear global_load_lds staging + swizzled
// ds_read_b128 is bank-conflict-free.
__global__ __launch_bounds__(256) void prep_w(
    const float* __restrict__ Wf, const float* __restrict__ Wi,
    const float* __restrict__ Wg, const float* __restrict__ Wo,
    unsigned char* __restrict__ wb)
{
    int chunk = blockIdx.x * 256 + threadIdx.x;   // 65536 chunks of 8 elems
    int g  = chunk >> 14;                         // 16384 chunks per gate
    int r  = chunk & 16383;
    int j  = r >> 6;                              // 64 chunks per j-row
    int k0 = (r & 63) * 8;
    const float* W = (g == 0) ? Wf : (g == 1) ? Wi : (g == 2) ? Wg : Wo;
    const float* src = W + (size_t)j * KTOT + k0;
    float4 a = *reinterpret_cast<const float4*>(src);
    float4 b = *reinterpret_cast<const float4*>(src + 4);
    union { short sh[8]; bf16x8 v; } u;
    u.sh[0] = f2bf(a.x); u.sh[1] = f2bf(a.y); u.sh[2] = f2bf(a.z); u.sh[3] = f2bf(a.w);
    u.sh[4] = f2bf(b.x); u.sh[5] = f2bf(b.y); u.sh[6] = f2bf(b.z); u.sh[7] = f2bf(b.w);
    size_t row_base = (size_t)(g * HID + j) * (KTOT * 2);
    int byte_in_row = (k0 * 2) ^ ((j & 7) << 4);
    *reinterpret_cast<bf16x8*>(wb + row_base + byte_in_row) = u.v;
}

// h0 fp32 [256][256] -> hb slice 0, same per-row swizzle (row stride 512 B)
__global__ __launch_bounds__(256) void prep_h0(
    const float* __restrict__ h0, unsigned char* __restrict__ hb)
{
    int chunk = blockIdx.x * 256 + threadIdx.x;   // 8192 chunks of 8
    int b  = chunk >> 5;
    int k0 = (chunk & 31) * 8;
    const float* src = h0 + (size_t)b * HID + k0;
    float4 a = *reinterpret_cast<const float4*>(src);
    float4 c = *reinterpret_cast<const float4*>(src + 4);
    union { short sh[8]; bf16x8 v; } u;
    u.sh[0] = f2bf(a.x); u.sh[1] = f2bf(a.y); u.sh[2] = f2bf(a.z); u.sh[3] = f2bf(a.w);
    u.sh[4] = f2bf(c.x); u.sh[5] = f2bf(c.y); u.sh[6] = f2bf(c.z); u.sh[7] = f2bf(c.w);
    *reinterpret_cast<bf16x8*>(hb + (size_t)b * 512 + ((k0 * 2) ^ ((b & 7) << 4))) = u.v;
}

// ---------------- per-step kernel ----------------
// grid: (16 j-tiles, 4 b-tiles); 256 threads = 4 waves.
// Wave w owns output tile [b0+16w .. +15] x [j0 .. j0+15], all 4 gates ->
// thread-local epilogue. Dynamic LDS 128 KiB:
//   W_lds  [64 rows (g*16+jj)][1024 B]  @ 0       (64 KiB)
//   Ax_lds [64 rows][512 B]             @ 65536   (32 KiB)
//   Ah_lds [64 rows][512 B]             @ 98304   (32 KiB)
__global__ __launch_bounds__(256) void lstm_step_mfma(
    const float* __restrict__ x,  const float* __restrict__ c0,
    const float* __restrict__ bf_, const float* __restrict__ bi_,
    const float* __restrict__ bg_, const float* __restrict__ bo_,
    const unsigned char* __restrict__ wb, unsigned char* __restrict__ hbuf,
    float* __restrict__ out, float* __restrict__ cx, float* __restrict__ hx,
    int s)
{
    extern __shared__ __align__(16) unsigned char smem[];
    unsigned char* W_lds  = smem;
    unsigned char* Ax_lds = smem + 65536;
    unsigned char* Ah_lds = smem + 98304;

    const int tid  = threadIdx.x;
    const int lane = tid & 63;
    const int w    = tid >> 6;
    const int j0   = blockIdx.x * 16;
    const int b0   = blockIdx.y * 64;

    // ---- stage W (64 KiB): wave w issues rows w*16+i, 1 KiB each
    #pragma unroll
    for (int i = 0; i < 16; ++i) {
        int row = w * 16 + i;                 // = g*16 + jj
        int g = row >> 4, jj = row & 15;
        const unsigned char* gp = wb + (size_t)(g * HID + j0 + jj) * 1024 + lane * 16;
        gload_lds16(gp, W_lds + row * 1024);
    }
    // ---- stage h (32 KiB): 1 KiB per issue, 8 per wave
    {
        const unsigned char* hsrc =
            hbuf + (size_t)(s & 1) * HB_BYTES + (size_t)b0 * 512;
        #pragma unroll
        for (int i = 0; i < 8; ++i) {
            int off = (w * 8 + i) * 1024;
            gload_lds16(hsrc + off + lane * 16, Ah_lds + off);
        }
    }
    // ---- stage x: fp32 load -> bf16 cvt -> swizzled ds_write_b128
    {
        const float* xs = x + ((size_t)s * BATCH + b0) * IND;
        #pragma unroll
        for (int i = 0; i < 8; ++i) {
            int chunk = tid + 256 * i;        // 2048 chunks of 8 elems
            int r  = chunk >> 5;
            int k0 = (chunk & 31) * 8;
            const float* p = xs + r * IND + k0;
            float4 a = *reinterpret_cast<const float4*>(p);
            float4 b = *reinterpret_cast<const float4*>(p + 4);
            union { short sh[8]; bf16x8 v; } u;
            u.sh[0] = f2bf(a.x); u.sh[1] = f2bf(a.y); u.sh[2] = f2bf(a.z); u.sh[3] = f2bf(a.w);
            u.sh[4] = f2bf(b.x); u.sh[5] = f2bf(b.y); u.sh[6] = f2bf(b.z); u.sh[7] = f2bf(b.w);
            *reinterpret_cast<bf16x8*>(
                Ax_lds + r * 512 + ((k0 * 2) ^ ((r & 7) << 4))) = u.v;
        }
    }
    __syncthreads();

    // ---- MFMA: K = 512 in 16 chunks of 32
    const int bw0  = w * 16;
    const int lrow = lane & 15;
    const int hi   = lane >> 4;
    const int arow = bw0 + lrow;
    const unsigned char* Axb = Ax_lds + arow * 512;
    const unsigned char* Ahb = Ah_lds + arow * 512;
    const int aswz = (arow & 7) << 4;
    const int bswz = (lrow & 7) << 4;

    f32x4 accF = {0.f, 0.f, 0.f, 0.f};
    f32x4 accI = {0.f, 0.f, 0.f, 0.f};
    f32x4 accG = {0.f, 0.f, 0.f, 0.f};
    f32x4 accO = {0.f, 0.f, 0.f, 0.f};

    #pragma unroll
    for (int kc = 0; kc < 16; ++kc) {
        const unsigned char* ap = (kc < 8)
            ? (Axb + ((kc * 64 + hi * 16) ^ aswz))
            : (Ahb + (((kc - 8) * 64 + hi * 16) ^ aswz));
        bf16x8 a = *reinterpret_cast<const bf16x8*>(ap);
        int wbyte = (kc * 64 + hi * 16) ^ bswz;
        bf16x8 vF = *reinterpret_cast<const bf16x8*>(W_lds + (0 * 16 + lrow) * 1024 + wbyte);
        bf16x8 vI = *reinterpret_cast<const bf16x8*>(W_lds + (1 * 16 + lrow) * 1024 + wbyte);
        bf16x8 vG = *reinterpret_cast<const bf16x8*>(W_lds + (2 * 16 + lrow) * 1024 + wbyte);
        bf16x8 vO = *reinterpret_cast<const bf16x8*>(W_lds + (3 * 16 + lrow) * 1024 + wbyte);
        accF = __builtin_amdgcn_mfma_f32_16x16x32_bf16(a, vF, accF, 0, 0, 0);
        accI = __builtin_amdgcn_mfma_f32_16x16x32_bf16(a, vI, accI, 0, 0, 0);
        accG = __builtin_amdgcn_mfma_f32_16x16x32_bf16(a, vG, accG, 0, 0, 0);
        accO = __builtin_amdgcn_mfma_f32_16x16x32_bf16(a, vO, accO, 0, 0, 0);
    }

    // ---- epilogue (thread-local; C layout col=lane&15, row=(lane>>4)*4+reg)
    const int j = j0 + lrow;
    const float biasF = bf_[j], biasI = bi_[j], biasG = bg_[j], biasO = bo_[j];
    unsigned char* hdst = hbuf + (size_t)((s + 1) & 1) * HB_BYTES;
    float* outp = out + (size_t)s * (BATCH * HID);

    #pragma unroll
    for (int r = 0; r < 4; ++r) {
        int b   = b0 + bw0 + hi * 4 + r;
        int idx = b * HID + j;
        float fg = sigmoid_f(accF[r] + biasF);
        float ig = sigmoid_f(accI[r] + biasI);
        float gg = tanh_f(accG[r] + biasG);
        float og = sigmoid_f(accO[r] + biasO);
        float cp = (s == 0) ? c0[idx] : cx[idx];
        float c  = fg * cp + ig * gg;
        cx[idx]  = c;
        float h  = og * tanh_f(c);
        outp[idx] = h;
        if (s == SEQ - 1) hx[idx] = h;
        *reinterpret_cast<short*>(
            hdst + (size_t)b * 512 + ((2 * j) ^ ((b & 7) << 4))) = f2bf(h);
    }
}

extern "C" void kernel_launch(void* const* d_in, const int* in_sizes, int n_in,
                              void* d_out, int out_size, void* d_ws, size_t ws_size,
                              hipStream_t stream) {
    const float* x  = (const float*)d_in[0];
    const float* h0 = (const float*)d_in[1];
    const float* c0 = (const float*)d_in[2];
    const float* Wf = (const float*)d_in[3];
    const float* bf = (const float*)d_in[4];
    const float* Wi = (const float*)d_in[5];
    const float* bi = (const float*)d_in[6];
    const float* Wg = (const float*)d_in[7];
    const float* bg = (const float*)d_in[8];
    const float* Wo = (const float*)d_in[9];
    const float* bo = (const float*)d_in[10];

    float* out = (float*)d_out;
    float* hx  = out + (size_t)SEQ * BATCH * HID;
    float* cx  = hx + BATCH * HID;

    unsigned char* wb = (unsigned char*)d_ws;
    unsigned char* hb = wb + WB_BYTES;

    prep_w<<<256, 256, 0, stream>>>(Wf, Wi, Wg, Wo, wb);
    prep_h0<<<32, 256, 0, stream>>>(h0, hb);

    dim3 grid(16, 4), block(256);
    for (int s = 0; s < SEQ; ++s) {
        lstm_step_mfma<<<grid, block, 131072, stream>>>(
            x, c0, bf, bi, bg, bo, wb, hb, out, cx, hx, s);
    }
}

// Round 3
// 8080.695 us; speedup vs baseline: 1.8792x; 1.2002x over previous
//
#include <hip/hip_runtime.h>
#include <hip/hip_bf16.h>
#include <math.h>

#define SEQ   1024
#define BATCH 256
#define IND   256
#define HID   256
#define KTOT  512
#define NGATE 4

// ws layout:
//   Wb    : bf16 [4][256][512], pre-swizzled rows (1 MiB)          @ 0
//   hring : bf16 [2][256 rows][512 B], pre-swizzled (2 x 128 KiB)  @ 1 MiB
//   flags : int  [64][32] (one cacheline-padded flag per block)    @ 1.25 MiB
#define WB_BYTES   (NGATE * HID * KTOT * 2)
#define HB_BYTES   (BATCH * 512)
#define FLAG_STRIDE 32

typedef float  f32x4  __attribute__((ext_vector_type(4)));
typedef short  bf16x8 __attribute__((ext_vector_type(8)));

__device__ __forceinline__ short f2bf(float x) {
    __hip_bfloat16 h = __float2bfloat16(x);
    return *reinterpret_cast<short*>(&h);
}

__device__ __forceinline__ void gload_lds16(const void* g, void* l) {
    __builtin_amdgcn_global_load_lds(
        (const __attribute__((address_space(1))) unsigned int*)g,
        (__attribute__((address_space(3))) unsigned int*)l, 16, 0, 0);
}

__device__ __forceinline__ float sigmoid_f(float z) {
    return 1.f / (1.f + __expf(-z));
}
__device__ __forceinline__ float tanh_f(float v) {
    return 2.f / (1.f + __expf(-2.f * v)) - 1.f;
}

// ---------------- prep kernels ----------------

__global__ __launch_bounds__(256) void prep_w(
    const float* __restrict__ Wf, const float* __restrict__ Wi,
    const float* __restrict__ Wg, const float* __restrict__ Wo,
    unsigned char* __restrict__ wb)
{
    int chunk = blockIdx.x * 256 + threadIdx.x;
    int g  = chunk >> 14;
    int r  = chunk & 16383;
    int j  = r >> 6;
    int k0 = (r & 63) * 8;
    const float* W = (g == 0) ? Wf : (g == 1) ? Wi : (g == 2) ? Wg : Wo;
    const float* src = W + (size_t)j * KTOT + k0;
    float4 a = *reinterpret_cast<const float4*>(src);
    float4 b = *reinterpret_cast<const float4*>(src + 4);
    union { short sh[8]; bf16x8 v; } u;
    u.sh[0] = f2bf(a.x); u.sh[1] = f2bf(a.y); u.sh[2] = f2bf(a.z); u.sh[3] = f2bf(a.w);
    u.sh[4] = f2bf(b.x); u.sh[5] = f2bf(b.y); u.sh[6] = f2bf(b.z); u.sh[7] = f2bf(b.w);
    size_t row_base = (size_t)(g * HID + j) * (KTOT * 2);
    int byte_in_row = (k0 * 2) ^ ((j & 7) << 4);
    *reinterpret_cast<bf16x8*>(wb + row_base + byte_in_row) = u.v;
}

// h0 -> ring slot 0 (h_{-1}); also zero the flags
__global__ __launch_bounds__(256) void prep_h0f(
    const float* __restrict__ h0, unsigned char* __restrict__ hb,
    int* __restrict__ flags)
{
    int chunk = blockIdx.x * 256 + threadIdx.x;   // 8192 chunks of 8
    int b  = chunk >> 5;
    int k0 = (chunk & 31) * 8;
    const float* src = h0 + (size_t)b * HID + k0;
    float4 a = *reinterpret_cast<const float4*>(src);
    float4 c = *reinterpret_cast<const float4*>(src + 4);
    union { short sh[8]; bf16x8 v; } u;
    u.sh[0] = f2bf(a.x); u.sh[1] = f2bf(a.y); u.sh[2] = f2bf(a.z); u.sh[3] = f2bf(a.w);
    u.sh[4] = f2bf(c.x); u.sh[5] = f2bf(c.y); u.sh[6] = f2bf(c.z); u.sh[7] = f2bf(c.w);
    *reinterpret_cast<bf16x8*>(hb + (size_t)b * 512 + ((k0 * 2) ^ ((b & 7) << 4))) = u.v;
    if (threadIdx.x < 64) flags[blockIdx.x * 64 + threadIdx.x] = 0;
}

// ---------------- persistent sequence kernel ----------------
// 64 blocks x 256 threads. blk -> B = blk&3 (b-group, 64 rows), J = blk>>2
// (16 j-cols). Weights resident in LDS for the whole sequence; c-state in
// registers; h exchanged via 2-deep global ring + per-block step flags
// (agent scope). Group B only syncs with its 15 siblings {4t+B}.
// LDS: W 64K @0 | Ax 32K @65536 | Ah 32K @98304
__global__ __launch_bounds__(256) void lstm_seq(
    const float* __restrict__ x,  const float* __restrict__ c0,
    const float* __restrict__ bf_, const float* __restrict__ bi_,
    const float* __restrict__ bg_, const float* __restrict__ bo_,
    const unsigned char* __restrict__ wb, unsigned char* __restrict__ hbuf,
    int* __restrict__ flags,
    float* __restrict__ out, float* __restrict__ hx, float* __restrict__ cxg)
{
    extern __shared__ __align__(16) unsigned char smem[];
    unsigned char* W_lds = smem;
    unsigned char* Ax    = smem + 65536;
    unsigned char* Ah    = smem + 98304;

    const int tid  = threadIdx.x;
    const int lane = tid & 63;
    const int w    = tid >> 6;
    const int blk  = blockIdx.x;
    const int B    = blk & 3;
    const int J    = blk >> 2;
    const int j0   = J * 16;
    const int b0   = B * 64;

    const int lrow = lane & 15;
    const int hi   = lane >> 4;
    const int j    = j0 + lrow;

    // ---- stage W once (64 KiB)
    #pragma unroll
    for (int i = 0; i < 16; ++i) {
        int row = w * 16 + i;                 // g*16 + jj
        int g = row >> 4, jj = row & 15;
        gload_lds16(wb + (size_t)(g * HID + j0 + jj) * 1024 + lane * 16,
                    W_lds + row * 1024);
    }

    // biases + c-state in registers
    const float biasF = bf_[j], biasI = bi_[j], biasG = bg_[j], biasO = bo_[j];
    float cst[4];
    #pragma unroll
    for (int r = 0; r < 4; ++r)
        cst[r] = c0[(b0 + w * 16 + hi * 4 + r) * HID + j];

    __syncthreads();   // W resident (drains gload_lds)

    const int arow = w * 16 + lrow;
    const unsigned char* Axb = Ax + arow * 512;
    const unsigned char* Ahb = Ah + arow * 512;
    const int aswz = (arow & 7) << 4;
    const int bswz = (lrow & 7) << 4;
    int* myflag = flags + blk * FLAG_STRIDE;

    for (int s = 0; s < SEQ; ++s) {
        // ---- issue x global loads early (latency hides under the poll)
        const float* xs = x + ((size_t)s * BATCH + b0) * IND;
        float4 xa[8], xb[8];
        #pragma unroll
        for (int i = 0; i < 8; ++i) {
            int chunk = tid + 256 * i;
            int r  = chunk >> 5;
            int k0 = (chunk & 31) * 8;
            const float* p = xs + r * IND + k0;
            xa[i] = *reinterpret_cast<const float4*>(p);
            xb[i] = *reinterpret_cast<const float4*>(p + 4);
        }

        // ---- wait for the 16 producers of h_{s-1} (group B siblings)
        if (lane < 16) {
            const int* fp = flags + (4 * lane + B) * FLAG_STRIDE;
            while (__hip_atomic_load(fp, __ATOMIC_ACQUIRE,
                                     __HIP_MEMORY_SCOPE_AGENT) < s) {
                __builtin_amdgcn_s_sleep(2);
            }
        }

        // ---- stage h_{s-1} (ring slot s&1), 8 KiB per wave
        const unsigned char* hsrc =
            hbuf + (size_t)(s & 1) * HB_BYTES + (size_t)b0 * 512;
        #pragma unroll
        for (int i = 0; i < 8; ++i)
            gload_lds16(hsrc + (w * 8 + i) * 1024 + lane * 16,
                        Ah + (w * 8 + i) * 1024);

        // ---- convert + swizzled ds_write of x
        #pragma unroll
        for (int i = 0; i < 8; ++i) {
            int chunk = tid + 256 * i;
            int r  = chunk >> 5;
            int k0 = (chunk & 31) * 8;
            union { short sh[8]; bf16x8 v; } u;
            u.sh[0] = f2bf(xa[i].x); u.sh[1] = f2bf(xa[i].y);
            u.sh[2] = f2bf(xa[i].z); u.sh[3] = f2bf(xa[i].w);
            u.sh[4] = f2bf(xb[i].x); u.sh[5] = f2bf(xb[i].y);
            u.sh[6] = f2bf(xb[i].z); u.sh[7] = f2bf(xb[i].w);
            *reinterpret_cast<bf16x8*>(
                Ax + r * 512 + ((k0 * 2) ^ ((r & 7) << 4))) = u.v;
        }
        __syncthreads();   // x in LDS, h landed

        // ---- MFMA: K = 512 (8 chunks x, 8 chunks h)
        f32x4 accF = {0.f, 0.f, 0.f, 0.f};
        f32x4 accI = {0.f, 0.f, 0.f, 0.f};
        f32x4 accG = {0.f, 0.f, 0.f, 0.f};
        f32x4 accO = {0.f, 0.f, 0.f, 0.f};
        #pragma unroll
        for (int kc = 0; kc < 16; ++kc) {
            const unsigned char* ap = (kc < 8)
                ? (Axb + ((kc * 64 + hi * 16) ^ aswz))
                : (Ahb + (((kc - 8) * 64 + hi * 16) ^ aswz));
            bf16x8 a = *reinterpret_cast<const bf16x8*>(ap);
            int wbyte = (kc * 64 + hi * 16) ^ bswz;
            bf16x8 vF = *reinterpret_cast<const bf16x8*>(W_lds + ( 0 + lrow) * 1024 + wbyte);
            bf16x8 vI = *reinterpret_cast<const bf16x8*>(W_lds + (16 + lrow) * 1024 + wbyte);
            bf16x8 vG = *reinterpret_cast<const bf16x8*>(W_lds + (32 + lrow) * 1024 + wbyte);
            bf16x8 vO = *reinterpret_cast<const bf16x8*>(W_lds + (48 + lrow) * 1024 + wbyte);
            accF = __builtin_amdgcn_mfma_f32_16x16x32_bf16(a, vF, accF, 0, 0, 0);
            accI = __builtin_amdgcn_mfma_f32_16x16x32_bf16(a, vI, accI, 0, 0, 0);
            accG = __builtin_amdgcn_mfma_f32_16x16x32_bf16(a, vG, accG, 0, 0, 0);
            accO = __builtin_amdgcn_mfma_f32_16x16x32_bf16(a, vO, accO, 0, 0, 0);
        }

        // ---- epilogue: gates, c-update (regs), h out + ring
        float* outp = out + (size_t)s * (BATCH * HID);
        unsigned char* hdst = hbuf + (size_t)((s + 1) & 1) * HB_BYTES;
        #pragma unroll
        for (int r = 0; r < 4; ++r) {
            int b   = b0 + w * 16 + hi * 4 + r;
            int idx = b * HID + j;
            float fg = sigmoid_f(accF[r] + biasF);
            float ig = sigmoid_f(accI[r] + biasI);
            float gg = tanh_f(accG[r] + biasG);
            float og = sigmoid_f(accO[r] + biasO);
            cst[r]   = fg * cst[r] + ig * gg;
            float h  = og * tanh_f(cst[r]);
            outp[idx] = h;
            *reinterpret_cast<short*>(
                hdst + (size_t)b * 512 + ((2 * j) ^ ((b & 7) << 4))) = f2bf(h);
            if (s == SEQ - 1) { hx[idx] = h; cxg[idx] = cst[r]; }
        }

        __syncthreads();   // drains all waves' stores; protects Ax/Ah reuse
        if (tid == 0)
            __hip_atomic_store(myflag, s + 1, __ATOMIC_RELEASE,
                               __HIP_MEMORY_SCOPE_AGENT);
    }
}

extern "C" void kernel_launch(void* const* d_in, const int* in_sizes, int n_in,
                              void* d_out, int out_size, void* d_ws, size_t ws_size,
                              hipStream_t stream) {
    const float* x  = (const float*)d_in[0];
    const float* h0 = (const float*)d_in[1];
    const float* c0 = (const float*)d_in[2];
    const float* Wf = (const float*)d_in[3];
    const float* bf = (const float*)d_in[4];
    const float* Wi = (const float*)d_in[5];
    const float* bi = (const float*)d_in[6];
    const float* Wg = (const float*)d_in[7];
    const float* bg = (const float*)d_in[8];
    const float* Wo = (const float*)d_in[9];
    const float* bo = (const float*)d_in[10];

    float* out = (float*)d_out;
    float* hx  = out + (size_t)SEQ * BATCH * HID;
    float* cx  = hx + BATCH * HID;

    unsigned char* wb = (unsigned char*)d_ws;
    unsigned char* hb = wb + WB_BYTES;
    int* flags = (int*)(hb + 2 * HB_BYTES);

    prep_w<<<256, 256, 0, stream>>>(Wf, Wi, Wg, Wo, wb);
    prep_h0f<<<32, 256, 0, stream>>>(h0, hb, flags);
    lstm_seq<<<64, 256, 131072, stream>>>(x, c0, bf, bi, bg, bo,
                                          wb, hb, flags, out, hx, cx);
}

// Round 4
// 5263.091 us; speedup vs baseline: 2.8852x; 1.5354x over previous
//
#include <hip/hip_runtime.h>
#include <hip/hip_bf16.h>
#include <math.h>

#define SEQ   1024
#define BATCH 256
#define IND   256
#define HID   256
#define NGATE 4

// ws layout:
//   wb    : bf16 [2 parts][4 gates][256 j][256 k], swizzled rows (1 MiB) @ 0
//   hring : bf16 [2][256 b][256 j] LINEAR (2 x 128 KiB)                  @ 1 MiB
//   flags : int  [64][32]                                                @ 1.25 MiB
#define WB_BYTES    (2 * NGATE * HID * 256 * 2)
#define HRING_HALF  (BATCH * HID * 2)
#define FLAG_STRIDE 32

typedef float  f32x4  __attribute__((ext_vector_type(4)));
typedef short  bf16x8 __attribute__((ext_vector_type(8)));

__device__ __forceinline__ short f2bf(float x) {
    __hip_bfloat16 h = __float2bfloat16(x);
    return *reinterpret_cast<short*>(&h);
}

__device__ __forceinline__ bf16x8 pack8(const float4& a, const float4& b) {
    union { short sh[8]; bf16x8 v; } u;
    u.sh[0] = f2bf(a.x); u.sh[1] = f2bf(a.y); u.sh[2] = f2bf(a.z); u.sh[3] = f2bf(a.w);
    u.sh[4] = f2bf(b.x); u.sh[5] = f2bf(b.y); u.sh[6] = f2bf(b.z); u.sh[7] = f2bf(b.w);
    return u.v;
}

__device__ __forceinline__ void gload_lds16(const void* g, void* l) {
    __builtin_amdgcn_global_load_lds(
        (const __attribute__((address_space(1))) unsigned int*)g,
        (__attribute__((address_space(3))) unsigned int*)l, 16, 0, 0);
}

__device__ __forceinline__ float sigmoid_f(float z) {
    return 1.f / (1.f + __expf(-z));
}
__device__ __forceinline__ float tanh_f(float v) {
    return 2.f / (1.f + __expf(-2.f * v)) - 1.f;
}

// ---------------- prep kernels ----------------

// W fp32 [256 j][512 k] x 4 gates -> wb bf16 [p][g][j][k'] with k' = k - 256p,
// 512B rows, byte (2k') ^ ((j&7)<<4)
__global__ __launch_bounds__(256) void prep_w(
    const float* __restrict__ Wf, const float* __restrict__ Wi,
    const float* __restrict__ Wg, const float* __restrict__ Wo,
    unsigned char* __restrict__ wb)
{
    int chunk = blockIdx.x * 256 + threadIdx.x;   // 65536 chunks of 8 floats
    int g  = chunk >> 14;
    int jj = (chunk >> 6) & 255;
    int k0 = (chunk & 63) * 8;
    int p  = k0 >> 8;
    int kk = k0 & 255;
    const float* W = (g == 0) ? Wf : (g == 1) ? Wi : (g == 2) ? Wg : Wo;
    const float* src = W + (size_t)jj * 512 + k0;
    float4 a = *reinterpret_cast<const float4*>(src);
    float4 b = *reinterpret_cast<const float4*>(src + 4);
    size_t dstrow = (size_t)((p * 4 + g) * 256 + jj);
    *reinterpret_cast<bf16x8*>(
        wb + dstrow * 512 + ((kk * 2) ^ ((jj & 7) << 4))) = pack8(a, b);
}

// h0 -> ring slot 0 (linear bf16), zero flags
__global__ __launch_bounds__(256) void prep_h0f(
    const float* __restrict__ h0, unsigned char* __restrict__ hring,
    int* __restrict__ flags)
{
    int chunk = blockIdx.x * 256 + threadIdx.x;   // 8192 chunks of 8
    int b  = chunk >> 5;
    int k0 = (chunk & 31) * 8;
    const float* src = h0 + (size_t)b * HID + k0;
    float4 a = *reinterpret_cast<const float4*>(src);
    float4 c = *reinterpret_cast<const float4*>(src + 4);
    *reinterpret_cast<bf16x8*>(hring + (size_t)b * 512 + k0 * 2) = pack8(a, c);
    int fi = blockIdx.x * 256 + threadIdx.x;
    if (fi < 64 * FLAG_STRIDE) flags[fi] = 0;
}

// ---------------- persistent sequence kernel ----------------
// 64 blocks x 256 threads; blk -> B = blk&3 (64 b-rows), J = blk>>2 (16 j).
// Per step: [x-part MFMA on pre-staged Ax] | bar | [cvt x(s+1); poll; coherent
// h loads -> Ah] | bar | [h-part MFMA; epilogue; h ring stores; x(s+2)
// prefetch] | bar | flag(s+1).  All cross-block traffic = RELAXED agent-scope
// atomics (no buffer_inv / buffer_wbl2); ordering via barrier vmcnt drain.
// LDS 128 KiB: W 64K @0 | Ax 32K @65536 | Ah 32K @98304
__global__ __launch_bounds__(256) void lstm_seq(
    const float* __restrict__ x,  const float* __restrict__ c0,
    const float* __restrict__ bf_, const float* __restrict__ bi_,
    const float* __restrict__ bg_, const float* __restrict__ bo_,
    const unsigned char* __restrict__ wb, unsigned char* __restrict__ hring,
    int* __restrict__ flags,
    float* __restrict__ out, float* __restrict__ hx, float* __restrict__ cxg)
{
    extern __shared__ __align__(16) unsigned char smem[];
    unsigned char* W_lds = smem;            // [p][g][jj] rows of 512B
    unsigned char* Ax    = smem + 65536;
    unsigned char* Ah    = smem + 98304;

    const int tid  = threadIdx.x;
    const int lane = tid & 63;
    const int w    = tid >> 6;
    const int blk  = blockIdx.x;
    const int B    = blk & 3;
    const int J    = blk >> 2;
    const int j0   = J * 16;
    const int b0   = B * 64;

    const int lrow = lane & 15;
    const int hi   = lane >> 4;
    const int j    = j0 + lrow;

    // ---- stage W once (64 x 1 KiB issues; covers both parts, all gates)
    #pragma unroll
    for (int i = 0; i < 16; ++i) {
        int idx = w * 16 + i;
        const unsigned char* src =
            wb + ((size_t)((idx >> 3) * 256 + j0 + (idx & 7) * 2)) * 512 + lane * 16;
        gload_lds16(src, W_lds + idx * 1024);
    }

    const float biasF = bf_[j], biasI = bi_[j], biasG = bg_[j], biasO = bo_[j];
    float cst[4];
    #pragma unroll
    for (int r = 0; r < 4; ++r)
        cst[r] = c0[(b0 + w * 16 + hi * 4 + r) * HID + j];

    // ---- stage x(0) into Ax; prefetch x(1) into regs
    float4 xa[8], xb[8];
    {
        const float* xs = x + (size_t)b0 * IND;
        #pragma unroll
        for (int i = 0; i < 8; ++i) {
            int c = tid + 256 * i;
            int r = c >> 5, k0 = (c & 31) * 8;
            const float* p = xs + r * IND + k0;
            xa[i] = *reinterpret_cast<const float4*>(p);
            xb[i] = *reinterpret_cast<const float4*>(p + 4);
        }
        #pragma unroll
        for (int i = 0; i < 8; ++i) {
            int c = tid + 256 * i;
            int r = c >> 5, k0 = (c & 31) * 8;
            *reinterpret_cast<bf16x8*>(
                Ax + r * 512 + ((k0 * 2) ^ ((r & 7) << 4))) = pack8(xa[i], xb[i]);
        }
        const float* xs1 = x + ((size_t)BATCH + b0) * IND;
        #pragma unroll
        for (int i = 0; i < 8; ++i) {
            int c = tid + 256 * i;
            int r = c >> 5, k0 = (c & 31) * 8;
            const float* p = xs1 + r * IND + k0;
            xa[i] = *reinterpret_cast<const float4*>(p);
            xb[i] = *reinterpret_cast<const float4*>(p + 4);
        }
    }

    const int arow = w * 16 + lrow;
    const unsigned char* Axb = Ax + arow * 512;
    const unsigned char* Ahb = Ah + arow * 512;
    const int aswz = (arow & 7) << 4;
    const int bswz = (lrow & 7) << 4;
    int* myflag = flags + blk * FLAG_STRIDE;

    __syncthreads();   // W + Ax resident

    for (int s = 0; s < SEQ; ++s) {
        f32x4 accF = {0.f, 0.f, 0.f, 0.f};
        f32x4 accI = {0.f, 0.f, 0.f, 0.f};
        f32x4 accG = {0.f, 0.f, 0.f, 0.f};
        f32x4 accO = {0.f, 0.f, 0.f, 0.f};

        // ---- phase 1: x-part MFMA (independent of siblings)
        #pragma unroll
        for (int kc = 0; kc < 8; ++kc) {
            bf16x8 a = *reinterpret_cast<const bf16x8*>(
                Axb + ((kc * 64 + hi * 16) ^ aswz));
            int wbyte = (kc * 64 + hi * 16) ^ bswz;
            const unsigned char* wr = W_lds + lrow * 512 + wbyte;   // part 0
            bf16x8 vF = *reinterpret_cast<const bf16x8*>(wr);
            bf16x8 vI = *reinterpret_cast<const bf16x8*>(wr + 8192);
            bf16x8 vG = *reinterpret_cast<const bf16x8*>(wr + 16384);
            bf16x8 vO = *reinterpret_cast<const bf16x8*>(wr + 24576);
            accF = __builtin_amdgcn_mfma_f32_16x16x32_bf16(a, vF, accF, 0, 0, 0);
            accI = __builtin_amdgcn_mfma_f32_16x16x32_bf16(a, vI, accI, 0, 0, 0);
            accG = __builtin_amdgcn_mfma_f32_16x16x32_bf16(a, vG, accG, 0, 0, 0);
            accO = __builtin_amdgcn_mfma_f32_16x16x32_bf16(a, vO, accO, 0, 0, 0);
        }
        __syncthreads();   // Ax reads done before overwrite

        // ---- phase 2: cvt x(s+1) -> Ax, poll siblings, coherent h -> Ah
        if (s + 1 < SEQ) {
            #pragma unroll
            for (int i = 0; i < 8; ++i) {
                int c = tid + 256 * i;
                int r = c >> 5, k0 = (c & 31) * 8;
                *reinterpret_cast<bf16x8*>(
                    Ax + r * 512 + ((k0 * 2) ^ ((r & 7) << 4))) = pack8(xa[i], xb[i]);
            }
        }
        if (lane < 16) {
            const int* fp = flags + (lane * 4 + B) * FLAG_STRIDE;
            while (__hip_atomic_load(fp, __ATOMIC_RELAXED,
                                     __HIP_MEMORY_SCOPE_AGENT) < s) {
                __builtin_amdgcn_s_sleep(1);
            }
        }
        asm volatile("" ::: "memory");
        {
            const unsigned char* hsrc =
                hring + (size_t)(s & 1) * HRING_HALF + (size_t)b0 * 512;
            #pragma unroll
            for (int i = 0; i < 8; ++i) {
                int c = tid + 256 * i;
                int r = c >> 5, k0b = (c & 31) * 16;
                const unsigned long long* p =
                    reinterpret_cast<const unsigned long long*>(hsrc + r * 512 + k0b);
                unsigned long long q0 = __hip_atomic_load(
                    p, __ATOMIC_RELAXED, __HIP_MEMORY_SCOPE_AGENT);
                unsigned long long q1 = __hip_atomic_load(
                    p + 1, __ATOMIC_RELAXED, __HIP_MEMORY_SCOPE_AGENT);
                union { unsigned long long q[2]; bf16x8 v; } u;
                u.q[0] = q0; u.q[1] = q1;
                *reinterpret_cast<bf16x8*>(
                    Ah + r * 512 + (k0b ^ ((r & 7) << 4))) = u.v;
            }
        }
        __syncthreads();   // Ah + new Ax resident

        // ---- phase 3: h-part MFMA
        #pragma unroll
        for (int kc = 0; kc < 8; ++kc) {
            bf16x8 a = *reinterpret_cast<const bf16x8*>(
                Ahb + ((kc * 64 + hi * 16) ^ aswz));
            int wbyte = (kc * 64 + hi * 16) ^ bswz;
            const unsigned char* wr = W_lds + 32768 + lrow * 512 + wbyte;  // part 1
            bf16x8 vF = *reinterpret_cast<const bf16x8*>(wr);
            bf16x8 vI = *reinterpret_cast<const bf16x8*>(wr + 8192);
            bf16x8 vG = *reinterpret_cast<const bf16x8*>(wr + 16384);
            bf16x8 vO = *reinterpret_cast<const bf16x8*>(wr + 24576);
            accF = __builtin_amdgcn_mfma_f32_16x16x32_bf16(a, vF, accF, 0, 0, 0);
            accI = __builtin_amdgcn_mfma_f32_16x16x32_bf16(a, vI, accI, 0, 0, 0);
            accG = __builtin_amdgcn_mfma_f32_16x16x32_bf16(a, vG, accG, 0, 0, 0);
            accO = __builtin_amdgcn_mfma_f32_16x16x32_bf16(a, vO, accO, 0, 0, 0);
        }

        // ---- epilogue: gates, c (regs), outputs, coherent h ring stores
        float* outp = out + (size_t)s * (BATCH * HID);
        unsigned char* hdst = hring + (size_t)((s + 1) & 1) * HRING_HALF;
        #pragma unroll
        for (int r = 0; r < 4; ++r) {
            int b   = b0 + w * 16 + hi * 4 + r;
            int idx = b * HID + j;
            float fg = sigmoid_f(accF[r] + biasF);
            float ig = sigmoid_f(accI[r] + biasI);
            float gg = tanh_f(accG[r] + biasG);
            float og = sigmoid_f(accO[r] + biasO);
            cst[r]   = fg * cst[r] + ig * gg;
            float h  = og * tanh_f(cst[r]);
            outp[idx] = h;
            unsigned short hb16 = (unsigned short)f2bf(h);
            __hip_atomic_store(
                reinterpret_cast<unsigned short*>(hdst + (size_t)b * 512 + j * 2),
                hb16, __ATOMIC_RELAXED, __HIP_MEMORY_SCOPE_AGENT);
            if (s == SEQ - 1) { hx[idx] = h; cxg[idx] = cst[r]; }
        }

        // ---- prefetch x(s+2)
        if (s + 2 < SEQ) {
            const float* xs = x + ((size_t)(s + 2) * BATCH + b0) * IND;
            #pragma unroll
            for (int i = 0; i < 8; ++i) {
                int c = tid + 256 * i;
                int r = c >> 5, k0 = (c & 31) * 8;
                const float* p = xs + r * IND + k0;
                xa[i] = *reinterpret_cast<const float4*>(p);
                xb[i] = *reinterpret_cast<const float4*>(p + 4);
            }
        }

        asm volatile("" ::: "memory");
        __syncthreads();   // hw drains vmcnt(0): h stores ACKed at coherent point
        if (tid == 0)
            __hip_atomic_store(myflag, s + 1, __ATOMIC_RELAXED,
                               __HIP_MEMORY_SCOPE_AGENT);
    }
}

extern "C" void kernel_launch(void* const* d_in, const int* in_sizes, int n_in,
                              void* d_out, int out_size, void* d_ws, size_t ws_size,
                              hipStream_t stream) {
    const float* x  = (const float*)d_in[0];
    const float* h0 = (const float*)d_in[1];
    const float* c0 = (const float*)d_in[2];
    const float* Wf = (const float*)d_in[3];
    const float* bf = (const float*)d_in[4];
    const float* Wi = (const float*)d_in[5];
    const float* bi = (const float*)d_in[6];
    const float* Wg = (const float*)d_in[7];
    const float* bg = (const float*)d_in[8];
    const float* Wo = (const float*)d_in[9];
    const float* bo = (const float*)d_in[10];

    float* out = (float*)d_out;
    float* hx  = out + (size_t)SEQ * BATCH * HID;
    float* cx  = hx + BATCH * HID;

    unsigned char* wb = (unsigned char*)d_ws;
    unsigned char* hb = wb + WB_BYTES;
    int* flags = (int*)(hb + 2 * HRING_HALF);

    prep_w<<<256, 256, 0, stream>>>(Wf, Wi, Wg, Wo, wb);
    prep_h0f<<<32, 256, 0, stream>>>(h0, hb, flags);
    lstm_seq<<<64, 256, 131072, stream>>>(x, c0, bf, bi, bg, bo,
                                          wb, hb, flags, out, hx, cx);
}